// Round 3
// baseline (325.805 us; speedup 1.0000x reference)
//
#include <hip/hip_runtime.h>
#include <hip/hip_bf16.h>
#include <stdint.h>

// BitLinear: y = (int8(x) @ unpack2bit(Wp)^T) * amax/(127*ws) + bias
// M=16384 tokens, K=2048, N=2048. Integer GEMM via mfma_i32_16x16x64_i8.
// R3: (a) quant = one wave/row, register-resident, no syncthreads;
//     (b) GEMM BK=128 (32KB LDS, 16 K-iters, 32 MFMA/barrier),
//         XOR swizzle slot = chunk ^ (row&7);
//     (c) grid x=m-tile so A-tile sharers land on one XCD (blockIdx%8).

typedef __attribute__((ext_vector_type(4))) int int4v;

#define GLOBAL_AS __attribute__((address_space(1)))
#define LDS_AS    __attribute__((address_space(3)))

static constexpr int MK = 2048;   // K (inner dim)
static constexpr int NN = 2048;   // out features
static constexpr int MM = 16384;  // tokens

// ---------------- activation quant: one WAVE per token row -----------------
__global__ void quant_kernel(const float* __restrict__ x,
                             const float* __restrict__ wscale,
                             signed char* __restrict__ xq,
                             float* __restrict__ rf) {
    const int wv   = (blockIdx.x * 256 + threadIdx.x) >> 6;  // global wave id
    const int lane = threadIdx.x & 63;
    const float ws = wscale[0];
    constexpr int NWAVES = 2048 * 256 / 64;                  // 8192

    for (int m = wv; m < MM; m += NWAVES) {
        const float4* xr = (const float4*)(x + (size_t)m * MK);
        float4 v[8];
        #pragma unroll
        for (int s = 0; s < 8; s++) v[s] = xr[s * 64 + lane];

        float amax = 0.0f;
        #pragma unroll
        for (int s = 0; s < 8; s++)
            amax = fmaxf(amax,
                   fmaxf(fmaxf(fabsf(v[s].x), fabsf(v[s].y)),
                         fmaxf(fabsf(v[s].z), fabsf(v[s].w))));
        #pragma unroll
        for (int off = 32; off >= 1; off >>= 1)
            amax = fmaxf(amax, __shfl_xor(amax, off));
        amax = fmaxf(amax, 1e-5f);
        const float scale = 127.0f / amax;
        if (lane == 0) rf[m] = amax / (127.0f * ws);

        auto q = [&](float f) -> int {
            float r = rintf(f * scale);          // round-half-to-even
            r = fminf(fmaxf(r, -128.0f), 127.0f);
            return (int)r;
        };
        int* xqr = (int*)(xq + (size_t)m * MK);
        #pragma unroll
        for (int s = 0; s < 8; s++) {
            int p = (q(v[s].x) & 255) | ((q(v[s].y) & 255) << 8) |
                    ((q(v[s].z) & 255) << 16) | ((q(v[s].w) & 255) << 24);
            xqr[s * 64 + lane] = p;
        }
    }
}

// ---------------- weight unpack: [512][2048] packed -> int8 W[2048][2048] ---
// w[i*512 + r][k] = ((packed[r][k] >> 2i) & 3) - 1
__global__ void unpack_kernel(const int* __restrict__ packed,
                              signed char* __restrict__ W) {
    const int idx = blockIdx.x * 256 + threadIdx.x;   // 0 .. 512*512
    const int r  = idx >> 9;        // packed row
    const int kq = idx & 511;       // k/4
    const int4 p = ((const int4*)packed)[idx];        // 4 consecutive k
    int* Wi = (int*)W;              // 512 ints per W row
    #pragma unroll
    for (int i = 0; i < 4; i++) {
        const int sh = 2 * i;
        int b0 = ((((p.x >> sh) & 3) - 1) & 255);
        int b1 = ((((p.y >> sh) & 3) - 1) & 255);
        int b2 = ((((p.z >> sh) & 3) - 1) & 255);
        int b3 = ((((p.w >> sh) & 3) - 1) & 255);
        Wi[(i * 512 + r) * 512 + kq] = b0 | (b1 << 8) | (b2 << 16) | (b3 << 24);
    }
}

// ---------------- int8 GEMM: C[m][n] = sum_k xq[m][k]*W[n][k] --------------
// 128x128 tile, BK=128 bytes, 4 waves in 2x2, per K-iter each wave does
// 2 k-steps x (4x4) mfma_i32_16x16x64_i8 = 32 MFMAs per barrier pair.
// LDS row = 128B; 16B chunk c of row r stored at slot c ^ (r&7).
__global__ void __launch_bounds__(256)
gemm_kernel(const signed char* __restrict__ xq,   // [M][K]
            const signed char* __restrict__ W,    // [N][K]
            const float* __restrict__ rf,         // [M]
            const float* __restrict__ bias,       // [N]
            float* __restrict__ out) {            // [M][N]
    constexpr int BK = 128;
    __shared__ __attribute__((aligned(16))) unsigned char As[128 * BK];
    __shared__ __attribute__((aligned(16))) unsigned char Bs[128 * BK];

    const int tid  = threadIdx.x;
    const int wave = tid >> 6;
    const int lane = tid & 63;
    const int m0 = blockIdx.x * 128;   // x = m-tile: A-sharers same XCD
    const int n0 = blockIdx.y * 128;

    // staging: round r (0..3), wave w covers rows r*32 + w*8 + (lane>>3),
    // LDS slot lane&7; global chunk fetched = (lane&7) ^ (row&7).
    const int srow  = lane >> 3;                       // 0..7 within wave part
    const int sbyte = ((lane & 7) ^ (srow & 7)) * 16;  // swizzled source chunk

    const int wm = (wave >> 1) * 64;   // wave's 64x64 subtile
    const int wn = (wave & 1) * 64;
    const int fr = lane & 15;          // fragment row (m or n) low bits
    const int fg = lane >> 4;          // k 16B-group within 64B step (0..3)

    int4v acc[4][4] = {};

    for (int k0 = 0; k0 < MK; k0 += BK) {
        #pragma unroll
        for (int r = 0; r < 4; r++) {
            const int row = r * 32 + wave * 8 + srow;
            const signed char* ga = xq + (size_t)(m0 + row) * MK + k0 + sbyte;
            __builtin_amdgcn_global_load_lds((const GLOBAL_AS void*)ga,
                                             (LDS_AS void*)(As + r * 4096 + wave * 1024),
                                             16, 0, 0);
            const signed char* gb = W + (size_t)(n0 + row) * MK + k0 + sbyte;
            __builtin_amdgcn_global_load_lds((const GLOBAL_AS void*)gb,
                                             (LDS_AS void*)(Bs + r * 4096 + wave * 1024),
                                             16, 0, 0);
        }
        __syncthreads();

        #pragma unroll
        for (int ks = 0; ks < 2; ks++) {
            const int c = ks * 4 + fg;                 // global 16B chunk 0..7
            int4v af[4], bf[4];
            #pragma unroll
            for (int i = 0; i < 4; i++) {
                const int ar = wm + i * 16 + fr;
                af[i] = *(const int4v*)(As + ar * BK + (c ^ (ar & 7)) * 16);
                const int br = wn + i * 16 + fr;
                bf[i] = *(const int4v*)(Bs + br * BK + (c ^ (br & 7)) * 16);
            }
            #pragma unroll
            for (int mt = 0; mt < 4; mt++)
                #pragma unroll
                for (int nt = 0; nt < 4; nt++)
                    acc[mt][nt] = __builtin_amdgcn_mfma_i32_16x16x64_i8(
                        af[mt], bf[nt], acc[mt][nt], 0, 0, 0);
        }
        __syncthreads();
    }

    // epilogue: C/D map col=lane&15, row=(lane>>4)*4+reg
    const int col   = lane & 15;
    const int rbase = (lane >> 4) * 4;
    #pragma unroll
    for (int mt = 0; mt < 4; mt++) {
        #pragma unroll
        for (int r = 0; r < 4; r++) {
            const int m = m0 + wm + mt * 16 + rbase + r;
            const float rfm = rf[m];
            #pragma unroll
            for (int nt = 0; nt < 4; nt++) {
                const int n = n0 + wn + nt * 16 + col;
                out[(size_t)m * NN + n] = (float)acc[mt][nt][r] * rfm + bias[n];
            }
        }
    }
}

extern "C" void kernel_launch(void* const* d_in, const int* in_sizes, int n_in,
                              void* d_out, int out_size, void* d_ws, size_t ws_size,
                              hipStream_t stream) {
    const float* x      = (const float*)d_in[0];
    const int*   packed = (const int*)d_in[1];
    const float* wscale = (const float*)d_in[2];
    const float* bias   = (const float*)d_in[3];
    float* out = (float*)d_out;

    // workspace: xq [16384*2048] i8 | W [2048*2048] i8 | rf [16384] f32
    signed char* xq = (signed char*)d_ws;
    signed char* W  = xq + (size_t)MM * MK;
    float*       rf = (float*)(W + (size_t)NN * MK);

    quant_kernel<<<2048, 256, 0, stream>>>(x, wscale, xq, rf);
    unpack_kernel<<<(512 * 512) / 256, 256, 0, stream>>>(packed, W);
    gemm_kernel<<<dim3(MM / 128, NN / 128), 256, 0, stream>>>(xq, W, rf, bias, out);
}